// Round 8
// baseline (558.777 us; speedup 1.0000x reference)
//
#include <hip/hip_runtime.h>

#define D_IN  64
#define D_HID 16
#define D_OUT 32

#define CPB    64          // cols per bucket (power of 2)
#define CPB_SH 6
#define NB_MAX 1600        // max buckets supported (N up to 102400)
#define BINB   128         // blocks in bincount/binfill passes

// ---------------------------------------------------------------------------
// A: per-(block,bucket) edge counts. Block blk owns edge chunk
//    [blk*chunk, min(E,(blk+1)*chunk)); LDS histogram, zero global atomics.
// ---------------------------------------------------------------------------
__global__ __launch_bounds__(256) void k_bincount(
        const int* __restrict__ col, int* __restrict__ cntB, int E, int NB) {
    __shared__ int hist[NB_MAX];
    for (int b = threadIdx.x; b < NB; b += 256) hist[b] = 0;
    __syncthreads();
    int chunk = (E + BINB - 1) / BINB;
    int s = blockIdx.x * chunk;
    int e = min(E, s + chunk);
    for (int i = s + threadIdx.x; i < e; i += 256)
        atomicAdd(&hist[col[i] >> CPB_SH], 1);
    __syncthreads();
    for (int b = threadIdx.x; b < NB; b += 256)
        cntB[b * BINB + blockIdx.x] = hist[b];
}

// ---------------------------------------------------------------------------
// B1: per-bucket exclusive scan over the BINB block counts (in place);
//     bucket total -> bb[b].
// ---------------------------------------------------------------------------
__global__ __launch_bounds__(BINB) void k_scanblk(int* __restrict__ cntB,
                                                  int* __restrict__ bb, int NB) {
    __shared__ int s[BINB];
    int b = blockIdx.x;
    int v = cntB[(size_t)b * BINB + threadIdx.x];
    s[threadIdx.x] = v;
    __syncthreads();
    for (int off = 1; off < BINB; off <<= 1) {
        int t = (threadIdx.x >= off) ? s[threadIdx.x - off] : 0;
        __syncthreads();
        s[threadIdx.x] += t;
        __syncthreads();
    }
    cntB[(size_t)b * BINB + threadIdx.x] = s[threadIdx.x] - v;  // exclusive
    if (threadIdx.x == BINB - 1) bb[b] = s[BINB - 1];           // total
}

// ---------------------------------------------------------------------------
// B2: exclusive scan of bucket totals (tiled, single block); bb[NB] = E.
// ---------------------------------------------------------------------------
__global__ void k_scanbase(int* __restrict__ bb, int NB) {
    __shared__ int s[512];
    __shared__ int basev;
    if (threadIdx.x == 0) basev = 0;
    __syncthreads();
    for (int start = 0; start < NB; start += 512) {
        int idx = start + threadIdx.x;
        int v = (idx < NB) ? bb[idx] : 0;
        s[threadIdx.x] = v;
        __syncthreads();
        for (int off = 1; off < 512; off <<= 1) {
            int t = (threadIdx.x >= off) ? s[threadIdx.x - off] : 0;
            __syncthreads();
            s[threadIdx.x] += t;
            __syncthreads();
        }
        if (idx < NB) bb[idx] = basev + s[threadIdx.x] - v;
        __syncthreads();
        if (threadIdx.x == 0) basev += s[511];
        __syncthreads();
    }
    if (threadIdx.x == 0) bb[NB] = basev;   // == E
}

// ---------------------------------------------------------------------------
// C: scatter edges into bucket-contiguous runs reserved per (block,bucket).
//    Pack (row | c_local<<20, w) into one int2. row < 2^20 (N=100000).
// ---------------------------------------------------------------------------
__global__ __launch_bounds__(256) void k_binfill(
        const int* __restrict__ ei, const float* __restrict__ w,
        const int* __restrict__ bb, const int* __restrict__ cntB,
        int2* __restrict__ binned, int E, int NB) {
    __shared__ int cur[NB_MAX];
    for (int b = threadIdx.x; b < NB; b += 256)
        cur[b] = bb[b] + cntB[(size_t)b * BINB + blockIdx.x];
    __syncthreads();
    int chunk = (E + BINB - 1) / BINB;
    int s = blockIdx.x * chunk;
    int e = min(E, s + chunk);
    for (int i = s + threadIdx.x; i < e; i += 256) {
        int c = ei[(size_t)E + i];
        int r = ei[i];
        float wt = w[i];
        int pos = atomicAdd(&cur[c >> CPB_SH], 1);
        binned[pos] = make_int2(r | ((c & (CPB - 1)) << 20), __float_as_int(wt));
    }
}

// ---------------------------------------------------------------------------
// D: weighted in-degree per node via per-bucket LDS accumulation;
//    dinv = rsqrt(1 + sum_w)  (self-loop weight 1 => always > 0).
// ---------------------------------------------------------------------------
__global__ __launch_bounds__(256) void k_deg(
        const int2* __restrict__ binned, const int* __restrict__ bb,
        float* __restrict__ dinv, int N) {
    __shared__ float wsum[CPB];
    if (threadIdx.x < CPB) wsum[threadIdx.x] = 0.f;
    __syncthreads();
    int b = blockIdx.x;
    int s = bb[b], e = bb[b + 1];
    for (int i = s + threadIdx.x; i < e; i += 256) {
        int2 v = binned[i];
        atomicAdd(&wsum[(v.x >> 20) & (CPB - 1)], __int_as_float(v.y));
    }
    __syncthreads();
    if (threadIdx.x < CPB) {
        int n = (b << CPB_SH) + threadIdx.x;
        if (n < N) dinv[n] = rsqrtf(1.0f + wsum[threadIdx.x]);
    }
}

// ---------------------------------------------------------------------------
// E: hs[n][f] = (x[n] . Wg[:,f]) * dinv[n].  16 nodes/block; x staged in LDS.
// ---------------------------------------------------------------------------
__global__ __launch_bounds__(256) void k_transform(
        const float4* __restrict__ x4,   // [N,16] float4 view of [N,64]
        const float* __restrict__ Wg,    // [64,16]
        const float* __restrict__ dinv,
        float* __restrict__ hs, int N) {
    __shared__ float Wl[D_IN * D_HID];   // 4KB
    __shared__ float xlf[16][68];        // padded x tile
    for (int i = threadIdx.x; i < D_IN * D_HID; i += 256) Wl[i] = Wg[i];
    const int f = threadIdx.x & 15, nl = threadIdx.x >> 4;
    for (int base = blockIdx.x * 16; base < N; base += gridDim.x * 16) {
        __syncthreads();                 // covers Wl (iter 0) + xlf reuse
        int n = base + nl;
        if (n < N) {
            float4 v = x4[(size_t)n * 16 + f];
            xlf[nl][f * 4 + 0] = v.x;
            xlf[nl][f * 4 + 1] = v.y;
            xlf[nl][f * 4 + 2] = v.z;
            xlf[nl][f * 4 + 3] = v.w;
        }
        __syncthreads();
        if (n < N) {
            float acc = 0.f;
#pragma unroll
            for (int k = 0; k < D_IN; ++k) acc += xlf[nl][k] * Wl[k * D_HID + f];
            hs[(size_t)n * D_HID + f] = acc * dinv[n];
        }
    }
}

// ---------------------------------------------------------------------------
// F: per-bucket aggregate in LDS + fused relu + output GEMM.
//    Epilogue math (FIXED vs R5): agg[c] = dinv[c]*(acc + hs_self) + bg —
//    hs_self = h*dinv already carries one dinv factor, so the self-loop
//    term is di*hs_self = di^2*h. R5 wrongly applied di twice (absmax 0.34).
// ---------------------------------------------------------------------------
__global__ __launch_bounds__(256) void k_aggout(
        const int2* __restrict__ binned, const int* __restrict__ bb,
        const float* __restrict__ hs, const float* __restrict__ dinv,
        const float* __restrict__ bg, const float* __restrict__ Wo,
        const float* __restrict__ bo, float* __restrict__ out, int N) {
    __shared__ float acc[CPB][D_HID + 1];
    __shared__ float Wl[D_HID * D_OUT];
    __shared__ float bgl[D_HID];
    __shared__ float bol[D_OUT];
    for (int i = threadIdx.x; i < CPB * (D_HID + 1); i += 256)
        ((float*)acc)[i] = 0.f;
    for (int i = threadIdx.x; i < D_HID * D_OUT; i += 256) Wl[i] = Wo[i];
    if (threadIdx.x < D_HID) bgl[threadIdx.x] = bg[threadIdx.x];
    if (threadIdx.x < D_OUT) bol[threadIdx.x] = bo[threadIdx.x];
    __syncthreads();

    int b = blockIdx.x;
    int s = bb[b], e = bb[b + 1];
    const int f = threadIdx.x & 15;
    // 16 edges per block-iteration; 2x unroll for independent gather chains.
    int i = s + (threadIdx.x >> 4);
    for (; i + 16 < e; i += 32) {
        int2 v0 = binned[i];
        int2 v1 = binned[i + 16];
        float h0 = hs[(size_t)(v0.x & 0xFFFFF) * D_HID + f];
        float h1 = hs[(size_t)(v1.x & 0xFFFFF) * D_HID + f];
        atomicAdd(&acc[(v0.x >> 20) & (CPB - 1)][f], h0 * __int_as_float(v0.y));
        atomicAdd(&acc[(v1.x >> 20) & (CPB - 1)][f], h1 * __int_as_float(v1.y));
    }
    if (i < e) {
        int2 v = binned[i];
        float h = hs[(size_t)(v.x & 0xFFFFF) * D_HID + f];
        atomicAdd(&acc[(v.x >> 20) & (CPB - 1)][f], h * __int_as_float(v.y));
    }
    __syncthreads();

    {   // relu + bias + self-loop fold: 16 nodes x 16 f per rep
        const int nl = threadIdx.x >> 4;
#pragma unroll
        for (int rep = 0; rep < CPB / 16; ++rep) {
            int cl = nl + rep * 16;
            int n = (b << CPB_SH) + cl;
            if (n < N) {
                float di = dinv[n];
                float v = di * (acc[cl][f] + hs[(size_t)n * D_HID + f]) + bgl[f];
                acc[cl][f] = fmaxf(v, 0.f);
            }
        }
    }
    __syncthreads();

    {   // out = emb @ Wo + bo : 8 nodes x 32 o per rep
        const int o  = threadIdx.x & 31;
        const int n2 = threadIdx.x >> 5;
#pragma unroll
        for (int rep = 0; rep < CPB / 8; ++rep) {
            int cl = n2 + rep * 8;
            int n = (b << CPB_SH) + cl;
            if (n < N) {
                float a = bol[o];
#pragma unroll
                for (int ff = 0; ff < D_HID; ++ff)
                    a += acc[cl][ff] * Wl[ff * D_OUT + o];
                out[(size_t)n * D_OUT + o] = a;
            }
        }
    }
}

// ---------------------------------------------------------------------------
// Workspace (floats), total 32.4MB (< R4-proven 33.2MB budget):
//   dinv[N] | bb[NB+1, padded even] | binned[2E] | hs[16N]
// cntB (NB*BINB ints = 0.8MB) OVERLAYS hs: dead after k_binfill, before
// k_transform writes hs (single stream => ordered). No memsets needed:
// every workspace word is written before it is read.
// ---------------------------------------------------------------------------
extern "C" void kernel_launch(void* const* d_in, const int* in_sizes, int n_in,
                              void* d_out, int out_size, void* d_ws, size_t ws_size,
                              hipStream_t stream) {
    const float* x  = (const float*)d_in[0];
    const int*   ei = (const int*)d_in[1];
    const float* ew = (const float*)d_in[2];
    const float* Wg = (const float*)d_in[3];
    const float* bg = (const float*)d_in[4];
    const float* Wo = (const float*)d_in[5];
    const float* bo = (const float*)d_in[6];
    float* out = (float*)d_out;

    const int N  = in_sizes[0] / D_IN;       // 100000
    const int E  = in_sizes[2];              // 3200000
    const int NB = (N + CPB - 1) >> CPB_SH;  // 1563 (<= NB_MAX)

    float* ws    = (float*)d_ws;
    float* dinv  = ws;                                   // N
    int*   bb    = (int*)(ws + N);                       // NB+1
    size_t bbe   = (size_t)N + (size_t)((NB + 2) & ~1);  // even float offset
    int2*  binned = (int2*)(ws + bbe);                   // 2E floats, 8B-aligned
    float* hs    = ws + bbe + (size_t)2 * E;             // 16N
    int*   cntB  = (int*)hs;                             // NB*BINB (overlay)

    k_bincount<<<BINB, 256, 0, stream>>>(ei + E, cntB, E, NB);
    k_scanblk <<<NB, BINB, 0, stream>>>(cntB, bb, NB);
    k_scanbase<<<1, 512, 0, stream>>>(bb, NB);
    k_binfill <<<BINB, 256, 0, stream>>>(ei, ew, bb, cntB, binned, E, NB);
    k_deg     <<<NB, 256, 0, stream>>>(binned, bb, dinv, N);
    k_transform<<<(N + 15) / 16, 256, 0, stream>>>((const float4*)x, Wg, dinv, hs, N);
    k_aggout  <<<NB, 256, 0, stream>>>(binned, bb, hs, dinv, bg, Wo, bo, out, N);
}